// Round 4
// baseline (223.416 us; speedup 1.0000x reference)
//
#include <hip/hip_runtime.h>
#include <hip/hip_bf16.h>

// Problem constants (fixed by setup_inputs): B=4, N=16384, M=128, C=128, S=512.
// Output layout (float32): pooled (B*M*S*(C+3)) then empty_flag (B*M) as 0.0/1.0.
#define BB   4
#define NN   16384
#define MM   128
#define CC   128
#define SS   512
#define CH   (CC + 3)      // 131
#define BM   (BB * MM)     // 512
#define WAVES 8            // waves per box in kernel A
#define CHUNK (NN / WAVES) // 2048 points per wave

// Session lessons (keep):
//  R5: fusing A+B into one kernel loses 8x gather TLP -> +20us. Don't.
//  R6: nontemporal output stores -> +7us. Don't.
//  R7: vectorizing A's point loads was neutral -> A is not VMEM-issue-bound.
//  R8: naive row-major LDS staging in B had 4-8 way bank conflicts.
//  R9: swizzled-LDS staging + dense dwordx4 stores: 195.4->191.9us.
//  R10: XCD-affinity remap of B's grid: NEUTRAL. (Kept: free, bijective.)
//  R11: {idx,x,y,z} record fusion (B: 12->8 load instrs, -1 dep hop): NEUTRAL.
//  R12 evidence: big 549-MB harness fills (4x output buf, ~83us) sit at
//      dispatch ID === 8 (mod 16) -> ONE per timed iteration. So
//      A + B + ~13 small dispatches ~= 105-109us, but the split is unknown
//      (neither kernel enters top-5; each < 80us; 3 B-changes all neutral).
//  R12 (this round): ATTRIBUTION PROBE, no optimization. Launch B twice
//      (idempotent, byte-identical output). dur_us delta == warm-B duration.
//      Pre-committed read: >=40 => B dominates, attack gather read path;
//      20-35 => B~25, remainder is A+overhead, double A next;
//      <=20 => B near write floor, compute final roofline.
#define SWZ(d) ((d) ^ (((d) >> 5) & 31))

// ---------------------------------------------------------------------------
// Kernel A: one block (8 waves, 512 thr) per box.  (unchanged)
// Each lane owns 4 consecutive points (48 B = 3 aligned float4 loads).
// Stable compaction via ballots; waves merge by prefix offsets (stable),
// wrap-fill idx[k]=idx[k%cnt]. Rotation test in double; z-test fp32
// bit-identical to numpy. Epilogue emits {idx,x,y,z} records (R11).
// ---------------------------------------------------------------------------
__global__ __launch_bounds__(512)
void box_sample_kernel(const float* __restrict__ points,  // (B,N,3)
                       const float* __restrict__ boxes,   // (B,M,7)
                       float4* __restrict__ rec_ws,       // (BM,SS) {idx,x,y,z}
                       int*  __restrict__ cnt_ws,         // (BM)
                       float* __restrict__ flag_out)      // (BM)
{
    const int box  = blockIdx.x;          // b*MM + m
    const int b    = box >> 7;            // MM = 128
    const int lane = threadIdx.x & 63;
    const int w    = threadIdx.x >> 6;    // wave 0..7

    const float4* P4 = (const float4*)(points + (size_t)b * NN * 3);
    const float*  bx = boxes + (size_t)box * 7;

    const float cx = bx[0], cy = bx[1], cz = bx[2];
    const float dx = bx[3], dy = bx[4], dz = bx[5], rz = bx[6];

    const float  czc = cz + dz * 0.5f;     // exact
    const float  hz  = dz * 0.5f;          // exact
    const double ca  = cos(-(double)rz);
    const double sa  = sin(-(double)rz);
    const double hx  = (double)dx * 0.5;
    const double hy  = (double)dy * 0.5;

    __shared__ int s_part[WAVES][SS];     // 16 KB
    __shared__ int s_cnt[WAVES];
    __shared__ int s_idx[SS];

    int cnt = 0;
    const int pbase = w * CHUNK;
    for (int i0 = 0; i0 < CHUNK; i0 += 256) {     // 8 outer iterations
        const int pt0 = pbase + i0 + 4 * lane;    // first of this lane's 4 points
        const int f4b = (pt0 * 3) >> 2;           // pt0 % 4 == 0 -> exact
        const float4 q0 = P4[f4b + 0];   // p0.x p0.y p0.z p1.x
        const float4 q1 = P4[f4b + 1];   // p1.y p1.z p2.x p2.y
        const float4 q2 = P4[f4b + 2];   // p2.z p3.x p3.y p3.z
        const float px[4] = {q0.x, q0.w, q1.z, q2.y};
        const float py[4] = {q0.y, q1.x, q1.w, q2.z};
        const float pz[4] = {q0.z, q1.y, q2.x, q2.w};

        unsigned m = 0;
        #pragma unroll
        for (int u = 0; u < 4; ++u) {
            const double sx = (double)px[u] - (double)cx;
            const double sy = (double)py[u] - (double)cy;
            const float  szf = pz[u] - czc;
            const double lx = sx * ca - sy * sa;
            const double ly = sx * sa + sy * ca;
            const bool inside = (fabs(lx) < hx) && (fabs(ly) < hy) && (fabsf(szf) <= hz);
            m |= (unsigned)inside << u;
        }

        unsigned long long M[4];
        #pragma unroll
        for (int u = 0; u < 4; ++u) M[u] = __ballot((m >> u) & 1u);

        const unsigned long long lower = (1ull << lane) - 1ull;
        int lanebase = cnt;
        #pragma unroll
        for (int u = 0; u < 4; ++u) lanebase += __popcll(M[u] & lower);

        #pragma unroll
        for (int u = 0; u < 4; ++u) {
            if ((m >> u) & 1u) {
                const int pos = lanebase + __builtin_popcount(m & ((1u << u) - 1u));
                if (pos < SS) s_part[w][pos] = pt0 + u;
            }
        }
        #pragma unroll
        for (int u = 0; u < 4; ++u) cnt += __popcll(M[u]);
    }
    if (lane == 0) s_cnt[w] = cnt;
    __syncthreads();

    int c[WAVES], off[WAVES];
    int total = 0;
    #pragma unroll
    for (int q = 0; q < WAVES; ++q) { c[q] = s_cnt[q]; off[q] = total; total += c[q]; }

    // merge segments into first min(total,SS) slots, stable order
    for (int k = threadIdx.x; k < SS; k += 512) {
        int v = 0;
        #pragma unroll
        for (int q = 0; q < WAVES; ++q) {
            const int r = k - off[q];
            if (r >= 0 && r < c[q]) v = s_part[q][r];
        }
        s_idx[k] = v;
    }
    __syncthreads();

    if (total > 0 && total < SS) {
        for (int k = total + threadIdx.x; k < SS; k += 512)
            s_idx[k] = s_idx[k % total];
        __syncthreads();
    }

    // Epilogue: emit {idx, x, y, z} records (point table is L2-hot).
    float4* dst = rec_ws + (size_t)box * SS;
    const float* Pb = points + (size_t)b * NN * 3;
    for (int k = threadIdx.x; k < SS; k += 512) {
        const int id = s_idx[k];
        float4 r;
        r.x = __int_as_float(id);
        r.y = Pb[id * 3 + 0];
        r.z = Pb[id * 3 + 1];
        r.w = Pb[id * 3 + 2];
        dst[k] = r;
    }
    if (threadIdx.x == 0) {
        cnt_ws[box]   = total;
        flag_out[box] = (total == 0) ? 1.0f : 0.0f;
    }
}

// ---------------------------------------------------------------------------
// Kernel B: record-driven gather with swizzled-LDS staging -> dense aligned
// float4 stores. Grid: 8192 flat workgroups, XCD-affinity remapped (R10).
// 256 threads = 8 half-waves; half-wave hw owns samples k = 4*hw + s.
// (unchanged this round — launched twice as the R12 attribution probe)
// ---------------------------------------------------------------------------
__global__ __launch_bounds__(256)
void gather_kernel(const float4* __restrict__ rec_ws,  // (BM,SS) {idx,x,y,z}
                   const float* __restrict__ feats,    // (B,N,C)
                   const int*   __restrict__ cnt_ws,   // (BM)
                   float* __restrict__ out)            // (BM,SS,CH)
{
    const int flat  = blockIdx.x;
    const int r     = flat & 7;
    const int b     = r >> 1;
    const int s2    = ((flat >> 3) << 1) | (r & 1);
    const int m     = s2 & (MM - 1);
    const int chunk = s2 >> 7;            // 0..15
    const int box   = (b << 7) + m;

    const int tid   = threadIdx.x;
    const int hw    = tid >> 5;           // half-wave 0..7
    const int j     = tid & 31;           // lane in half-wave

    __shared__ float s_out[32 * CH];      // 4192 dwords = 16768 B

    const float scale = (cnt_ws[box] > 0) ? 1.0f : 0.0f;
    const float4* recp = rec_ws + (size_t)box * SS + chunk * 32;

    float4 rec[4];
    #pragma unroll
    for (int s = 0; s < 4; ++s) rec[s] = recp[4 * hw + s];   // broadcast loads

    const float4* F4 = (const float4*)(feats + (size_t)b * NN * CC);

    float4 v[4];
    #pragma unroll
    for (int s = 0; s < 4; ++s) v[s] = F4[__float_as_int(rec[s].x) * 32 + j];

    // Swizzled staging. Row k = 4*hw+s owns dwords [k*131, k*131+131).
    #pragma unroll
    for (int s = 0; s < 4; ++s) {
        const int k    = 4 * hw + s;
        const int base = k * CH + 3 + 4 * j;
        s_out[SWZ(base + 0)] = v[s].x * scale;
        s_out[SWZ(base + 1)] = v[s].y * scale;
        s_out[SWZ(base + 2)] = v[s].z * scale;
        s_out[SWZ(base + 3)] = v[s].w * scale;
        if (j < 3) {
            const float p = (j == 0) ? rec[s].y : ((j == 1) ? rec[s].z : rec[s].w);
            s_out[SWZ(k * CH + j)] = p * scale;
        }
    }
    __syncthreads();

    // Dense aligned output: 1048 float4s over the chunk's contiguous 16768 B.
    float* dst = out + (size_t)box * SS * CH + (size_t)chunk * 32 * CH;
    for (int t = tid; t < (32 * CH) / 4; t += 256) {
        const int dw = 4 * t;
        float4 o;
        o.x = s_out[SWZ(dw + 0)];
        o.y = s_out[SWZ(dw + 1)];
        o.z = s_out[SWZ(dw + 2)];
        o.w = s_out[SWZ(dw + 3)];
        ((float4*)dst)[t] = o;
    }
}

extern "C" void kernel_launch(void* const* d_in, const int* in_sizes, int n_in,
                              void* d_out, int out_size, void* d_ws, size_t ws_size,
                              hipStream_t stream) {
    const float* points = (const float*)d_in[0];
    const float* feats  = (const float*)d_in[1];
    const float* boxes  = (const float*)d_in[2];
    // d_in[3] = num_sampled_points, fixed at 512 by setup_inputs.

    float4* rec_ws = (float4*)d_ws;                  // BM*SS float4 = 4 MiB
    int*    cnt_ws = (int*)(rec_ws + (size_t)BM * SS); // BM ints
    float*  out      = (float*)d_out;
    float*  flag_out = out + (size_t)BM * SS * CH;   // empty_flag as float 0/1

    box_sample_kernel<<<BM, 512, 0, stream>>>(points, boxes, rec_ws, cnt_ws, flag_out);
    gather_kernel<<<BM * (SS / 32), 256, 0, stream>>>(rec_ws, feats, cnt_ws, out);
    // R12 attribution probe: second, idempotent B launch. dur_us delta vs
    // 192.0 == warm-B duration. Remove next round.
    gather_kernel<<<BM * (SS / 32), 256, 0, stream>>>(rec_ws, feats, cnt_ws, out);
}

// Round 6
// 203.891 us; speedup vs baseline: 1.0958x; 1.0958x over previous
//
#include <hip/hip_runtime.h>
#include <hip/hip_bf16.h>

// Problem constants (fixed by setup_inputs): B=4, N=16384, M=128, C=128, S=512.
// Output layout (float32): pooled (B*M*S*(C+3)) then empty_flag (B*M) as 0.0/1.0.
#define BB   4
#define NN   16384
#define MM   128
#define CC   128
#define SS   512
#define CH   (CC + 3)      // 131
#define BM   (BB * MM)     // 512
#define WAVES 8            // waves per box in kernel A
#define CHUNK (NN / WAVES) // 2048 points per wave

// Session lessons (keep):
//  R5: fusing A+B into one kernel loses 8x gather TLP -> +20us. Don't.
//  R6: nontemporal output stores -> +7us. Don't.
//  R7: vectorizing A's point loads was neutral -> A is not VMEM-issue-bound.
//  R8: naive row-major LDS staging in B had 4-8 way bank conflicts.
//  R9: swizzled-LDS staging + dense dwordx4 stores: 195.4->191.9us.
//  R10: XCD-affinity remap of B's grid: NEUTRAL. (Kept: free, bijective.)
//  R11: {idx,x,y,z} record fusion (B: 12->8 load instrs, -1 dep hop): NEUTRAL.
//  R12 PROBE RESULT: B x2 => 192.0 -> 223.4us => warm-B = 31.4us. B is within
//      ~10us of its 21us compulsory-write floor (137MB @ ~6.7TB/s measured
//      fill ceiling) -> explains R9/R10/R11 neutrality. Timed window per
//      iteration = 83us re-poison fill + ~13 small harness dispatches + A + B
//      => A + small-dispatch overhead ~= 70-78us, split unknown.
//  R13 (RETRY — R5's GPU acquisition timed out, probe never ran):
//      final ATTRIBUTION PROBE. Launch A twice (idempotent).
//      dur_us - 192 == warm-A. Pre-committed: >=40 => optimize A (f64 chain,
//      2-blocks/CU shape); 15-35 => one squeeze then stop; <=10 => harness
//      overhead dominates, declare ROOFLINE with arithmetic.
#define SWZ(d) ((d) ^ (((d) >> 5) & 31))

// ---------------------------------------------------------------------------
// Kernel A: one block (8 waves, 512 thr) per box.  (unchanged)
// Each lane owns 4 consecutive points (48 B = 3 aligned float4 loads).
// Stable compaction via ballots; waves merge by prefix offsets (stable),
// wrap-fill idx[k]=idx[k%cnt]. Rotation test in double; z-test fp32
// bit-identical to numpy. Epilogue emits {idx,x,y,z} records (R11).
// ---------------------------------------------------------------------------
__global__ __launch_bounds__(512)
void box_sample_kernel(const float* __restrict__ points,  // (B,N,3)
                       const float* __restrict__ boxes,   // (B,M,7)
                       float4* __restrict__ rec_ws,       // (BM,SS) {idx,x,y,z}
                       int*  __restrict__ cnt_ws,         // (BM)
                       float* __restrict__ flag_out)      // (BM)
{
    const int box  = blockIdx.x;          // b*MM + m
    const int b    = box >> 7;            // MM = 128
    const int lane = threadIdx.x & 63;
    const int w    = threadIdx.x >> 6;    // wave 0..7

    const float4* P4 = (const float4*)(points + (size_t)b * NN * 3);
    const float*  bx = boxes + (size_t)box * 7;

    const float cx = bx[0], cy = bx[1], cz = bx[2];
    const float dx = bx[3], dy = bx[4], dz = bx[5], rz = bx[6];

    const float  czc = cz + dz * 0.5f;     // exact
    const float  hz  = dz * 0.5f;          // exact
    const double ca  = cos(-(double)rz);
    const double sa  = sin(-(double)rz);
    const double hx  = (double)dx * 0.5;
    const double hy  = (double)dy * 0.5;

    __shared__ int s_part[WAVES][SS];     // 16 KB
    __shared__ int s_cnt[WAVES];
    __shared__ int s_idx[SS];

    int cnt = 0;
    const int pbase = w * CHUNK;
    for (int i0 = 0; i0 < CHUNK; i0 += 256) {     // 8 outer iterations
        const int pt0 = pbase + i0 + 4 * lane;    // first of this lane's 4 points
        const int f4b = (pt0 * 3) >> 2;           // pt0 % 4 == 0 -> exact
        const float4 q0 = P4[f4b + 0];   // p0.x p0.y p0.z p1.x
        const float4 q1 = P4[f4b + 1];   // p1.y p1.z p2.x p2.y
        const float4 q2 = P4[f4b + 2];   // p2.z p3.x p3.y p3.z
        const float px[4] = {q0.x, q0.w, q1.z, q2.y};
        const float py[4] = {q0.y, q1.x, q1.w, q2.z};
        const float pz[4] = {q0.z, q1.y, q2.x, q2.w};

        unsigned m = 0;
        #pragma unroll
        for (int u = 0; u < 4; ++u) {
            const double sx = (double)px[u] - (double)cx;
            const double sy = (double)py[u] - (double)cy;
            const float  szf = pz[u] - czc;
            const double lx = sx * ca - sy * sa;
            const double ly = sx * sa + sy * ca;
            const bool inside = (fabs(lx) < hx) && (fabs(ly) < hy) && (fabsf(szf) <= hz);
            m |= (unsigned)inside << u;
        }

        unsigned long long M[4];
        #pragma unroll
        for (int u = 0; u < 4; ++u) M[u] = __ballot((m >> u) & 1u);

        const unsigned long long lower = (1ull << lane) - 1ull;
        int lanebase = cnt;
        #pragma unroll
        for (int u = 0; u < 4; ++u) lanebase += __popcll(M[u] & lower);

        #pragma unroll
        for (int u = 0; u < 4; ++u) {
            if ((m >> u) & 1u) {
                const int pos = lanebase + __builtin_popcount(m & ((1u << u) - 1u));
                if (pos < SS) s_part[w][pos] = pt0 + u;
            }
        }
        #pragma unroll
        for (int u = 0; u < 4; ++u) cnt += __popcll(M[u]);
    }
    if (lane == 0) s_cnt[w] = cnt;
    __syncthreads();

    int c[WAVES], off[WAVES];
    int total = 0;
    #pragma unroll
    for (int q = 0; q < WAVES; ++q) { c[q] = s_cnt[q]; off[q] = total; total += c[q]; }

    // merge segments into first min(total,SS) slots, stable order
    for (int k = threadIdx.x; k < SS; k += 512) {
        int v = 0;
        #pragma unroll
        for (int q = 0; q < WAVES; ++q) {
            const int r = k - off[q];
            if (r >= 0 && r < c[q]) v = s_part[q][r];
        }
        s_idx[k] = v;
    }
    __syncthreads();

    if (total > 0 && total < SS) {
        for (int k = total + threadIdx.x; k < SS; k += 512)
            s_idx[k] = s_idx[k % total];
        __syncthreads();
    }

    // Epilogue: emit {idx, x, y, z} records (point table is L2-hot).
    float4* dst = rec_ws + (size_t)box * SS;
    const float* Pb = points + (size_t)b * NN * 3;
    for (int k = threadIdx.x; k < SS; k += 512) {
        const int id = s_idx[k];
        float4 r;
        r.x = __int_as_float(id);
        r.y = Pb[id * 3 + 0];
        r.z = Pb[id * 3 + 1];
        r.w = Pb[id * 3 + 2];
        dst[k] = r;
    }
    if (threadIdx.x == 0) {
        cnt_ws[box]   = total;
        flag_out[box] = (total == 0) ? 1.0f : 0.0f;
    }
}

// ---------------------------------------------------------------------------
// Kernel B: record-driven gather with swizzled-LDS staging -> dense aligned
// float4 stores. Grid: 8192 flat workgroups, XCD-affinity remapped (R10).
// 256 threads = 8 half-waves; half-wave hw owns samples k = 4*hw + s.
// (unchanged; measured warm = 31.4us in R12, ~10us above compulsory floor)
// ---------------------------------------------------------------------------
__global__ __launch_bounds__(256)
void gather_kernel(const float4* __restrict__ rec_ws,  // (BM,SS) {idx,x,y,z}
                   const float* __restrict__ feats,    // (B,N,C)
                   const int*   __restrict__ cnt_ws,   // (BM)
                   float* __restrict__ out)            // (BM,SS,CH)
{
    const int flat  = blockIdx.x;
    const int r     = flat & 7;
    const int b     = r >> 1;
    const int s2    = ((flat >> 3) << 1) | (r & 1);
    const int m     = s2 & (MM - 1);
    const int chunk = s2 >> 7;            // 0..15
    const int box   = (b << 7) + m;

    const int tid   = threadIdx.x;
    const int hw    = tid >> 5;           // half-wave 0..7
    const int j     = tid & 31;           // lane in half-wave

    __shared__ float s_out[32 * CH];      // 4192 dwords = 16768 B

    const float scale = (cnt_ws[box] > 0) ? 1.0f : 0.0f;
    const float4* recp = rec_ws + (size_t)box * SS + chunk * 32;

    float4 rec[4];
    #pragma unroll
    for (int s = 0; s < 4; ++s) rec[s] = recp[4 * hw + s];   // broadcast loads

    const float4* F4 = (const float4*)(feats + (size_t)b * NN * CC);

    float4 v[4];
    #pragma unroll
    for (int s = 0; s < 4; ++s) v[s] = F4[__float_as_int(rec[s].x) * 32 + j];

    // Swizzled staging. Row k = 4*hw+s owns dwords [k*131, k*131+131).
    #pragma unroll
    for (int s = 0; s < 4; ++s) {
        const int k    = 4 * hw + s;
        const int base = k * CH + 3 + 4 * j;
        s_out[SWZ(base + 0)] = v[s].x * scale;
        s_out[SWZ(base + 1)] = v[s].y * scale;
        s_out[SWZ(base + 2)] = v[s].z * scale;
        s_out[SWZ(base + 3)] = v[s].w * scale;
        if (j < 3) {
            const float p = (j == 0) ? rec[s].y : ((j == 1) ? rec[s].z : rec[s].w);
            s_out[SWZ(k * CH + j)] = p * scale;
        }
    }
    __syncthreads();

    // Dense aligned output: 1048 float4s over the chunk's contiguous 16768 B.
    float* dst = out + (size_t)box * SS * CH + (size_t)chunk * 32 * CH;
    for (int t = tid; t < (32 * CH) / 4; t += 256) {
        const int dw = 4 * t;
        float4 o;
        o.x = s_out[SWZ(dw + 0)];
        o.y = s_out[SWZ(dw + 1)];
        o.z = s_out[SWZ(dw + 2)];
        o.w = s_out[SWZ(dw + 3)];
        ((float4*)dst)[t] = o;
    }
}

extern "C" void kernel_launch(void* const* d_in, const int* in_sizes, int n_in,
                              void* d_out, int out_size, void* d_ws, size_t ws_size,
                              hipStream_t stream) {
    const float* points = (const float*)d_in[0];
    const float* feats  = (const float*)d_in[1];
    const float* boxes  = (const float*)d_in[2];
    // d_in[3] = num_sampled_points, fixed at 512 by setup_inputs.

    float4* rec_ws = (float4*)d_ws;                  // BM*SS float4 = 4 MiB
    int*    cnt_ws = (int*)(rec_ws + (size_t)BM * SS); // BM ints
    float*  out      = (float*)d_out;
    float*  flag_out = out + (size_t)BM * SS * CH;   // empty_flag as float 0/1

    box_sample_kernel<<<BM, 512, 0, stream>>>(points, boxes, rec_ws, cnt_ws, flag_out);
    // R13 attribution probe: second, idempotent A launch. dur_us delta vs
    // 192.0 == warm-A duration. Remove next round.
    box_sample_kernel<<<BM, 512, 0, stream>>>(points, boxes, rec_ws, cnt_ws, flag_out);
    gather_kernel<<<BM * (SS / 32), 256, 0, stream>>>(rec_ws, feats, cnt_ws, out);
}

// Round 7
// 191.963 us; speedup vs baseline: 1.1638x; 1.0621x over previous
//
#include <hip/hip_runtime.h>
#include <hip/hip_bf16.h>

// Problem constants (fixed by setup_inputs): B=4, N=16384, M=128, C=128, S=512.
// Output layout (float32): pooled (B*M*S*(C+3)) then empty_flag (B*M) as 0.0/1.0.
#define BB   4
#define NN   16384
#define MM   128
#define CC   128
#define SS   512
#define CH   (CC + 3)      // 131
#define BM   (BB * MM)     // 512
#define WAVES 8            // waves per box in kernel A
#define CHUNK (NN / WAVES) // 2048 points per wave

// Session ledger (final):
//  R5: fusing A+B into one kernel loses 8x gather TLP -> +20us. Don't.
//  R6: nontemporal output stores -> +7us. Don't.
//  R7: vectorizing A's point loads was neutral -> A is not VMEM-issue-bound.
//  R8: naive row-major LDS staging in B had 4-8 way bank conflicts.
//  R9: swizzled-LDS staging + dense dwordx4 stores: 195.4->191.9us.
//  R10: XCD-affinity remap of B's grid: NEUTRAL. (Kept: free, bijective.)
//  R11: {idx,x,y,z} record fusion (B: 12->8 load instrs, -1 dep hop): NEUTRAL.
//  R12 PROBE: B x2 => warm-B = 31.4us (floor ~25-28: 137MB writes @6.7TB/s
//      + ~8us L3 gather reads). Explains R9/R10/R11 neutrality.
//  R13 PROBE: A x2 => 192.0 -> 203.9us => warm-A = 11.9us (VALU-bound
//      ballot/compaction, floor ~6-8us).
//  FINAL ACCOUNTING of the 192us timed window:
//      ~83us harness re-poison fill (549MB = 4x output, 84-86% HBM peak)
//    + ~60us small harness dispatch overhead (~13 dispatches)
//    + ~31us kernel B + ~12us kernel A.
//      Controllable headroom ~8-10us (~5%) at correctness risk -> STOP.
//      This file restores the exact R11-verified config (192.0us, absmax 0).
#define SWZ(d) ((d) ^ (((d) >> 5) & 31))

// ---------------------------------------------------------------------------
// Kernel A: one block (8 waves, 512 thr) per box.
// Each lane owns 4 consecutive points (48 B = 3 aligned float4 loads).
// Stable compaction via ballots; waves merge by prefix offsets (stable),
// wrap-fill idx[k]=idx[k%cnt]. Rotation test in double; z-test fp32
// bit-identical to numpy. Epilogue emits {idx,x,y,z} records (R11).
// ---------------------------------------------------------------------------
__global__ __launch_bounds__(512)
void box_sample_kernel(const float* __restrict__ points,  // (B,N,3)
                       const float* __restrict__ boxes,   // (B,M,7)
                       float4* __restrict__ rec_ws,       // (BM,SS) {idx,x,y,z}
                       int*  __restrict__ cnt_ws,         // (BM)
                       float* __restrict__ flag_out)      // (BM)
{
    const int box  = blockIdx.x;          // b*MM + m
    const int b    = box >> 7;            // MM = 128
    const int lane = threadIdx.x & 63;
    const int w    = threadIdx.x >> 6;    // wave 0..7

    const float4* P4 = (const float4*)(points + (size_t)b * NN * 3);
    const float*  bx = boxes + (size_t)box * 7;

    const float cx = bx[0], cy = bx[1], cz = bx[2];
    const float dx = bx[3], dy = bx[4], dz = bx[5], rz = bx[6];

    const float  czc = cz + dz * 0.5f;     // exact
    const float  hz  = dz * 0.5f;          // exact
    const double ca  = cos(-(double)rz);
    const double sa  = sin(-(double)rz);
    const double hx  = (double)dx * 0.5;
    const double hy  = (double)dy * 0.5;

    __shared__ int s_part[WAVES][SS];     // 16 KB
    __shared__ int s_cnt[WAVES];
    __shared__ int s_idx[SS];

    int cnt = 0;
    const int pbase = w * CHUNK;
    for (int i0 = 0; i0 < CHUNK; i0 += 256) {     // 8 outer iterations
        const int pt0 = pbase + i0 + 4 * lane;    // first of this lane's 4 points
        const int f4b = (pt0 * 3) >> 2;           // pt0 % 4 == 0 -> exact
        const float4 q0 = P4[f4b + 0];   // p0.x p0.y p0.z p1.x
        const float4 q1 = P4[f4b + 1];   // p1.y p1.z p2.x p2.y
        const float4 q2 = P4[f4b + 2];   // p2.z p3.x p3.y p3.z
        const float px[4] = {q0.x, q0.w, q1.z, q2.y};
        const float py[4] = {q0.y, q1.x, q1.w, q2.z};
        const float pz[4] = {q0.z, q1.y, q2.x, q2.w};

        unsigned m = 0;
        #pragma unroll
        for (int u = 0; u < 4; ++u) {
            const double sx = (double)px[u] - (double)cx;
            const double sy = (double)py[u] - (double)cy;
            const float  szf = pz[u] - czc;
            const double lx = sx * ca - sy * sa;
            const double ly = sx * sa + sy * ca;
            const bool inside = (fabs(lx) < hx) && (fabs(ly) < hy) && (fabsf(szf) <= hz);
            m |= (unsigned)inside << u;
        }

        unsigned long long M[4];
        #pragma unroll
        for (int u = 0; u < 4; ++u) M[u] = __ballot((m >> u) & 1u);

        const unsigned long long lower = (1ull << lane) - 1ull;
        int lanebase = cnt;
        #pragma unroll
        for (int u = 0; u < 4; ++u) lanebase += __popcll(M[u] & lower);

        #pragma unroll
        for (int u = 0; u < 4; ++u) {
            if ((m >> u) & 1u) {
                const int pos = lanebase + __builtin_popcount(m & ((1u << u) - 1u));
                if (pos < SS) s_part[w][pos] = pt0 + u;
            }
        }
        #pragma unroll
        for (int u = 0; u < 4; ++u) cnt += __popcll(M[u]);
    }
    if (lane == 0) s_cnt[w] = cnt;
    __syncthreads();

    int c[WAVES], off[WAVES];
    int total = 0;
    #pragma unroll
    for (int q = 0; q < WAVES; ++q) { c[q] = s_cnt[q]; off[q] = total; total += c[q]; }

    // merge segments into first min(total,SS) slots, stable order
    for (int k = threadIdx.x; k < SS; k += 512) {
        int v = 0;
        #pragma unroll
        for (int q = 0; q < WAVES; ++q) {
            const int r = k - off[q];
            if (r >= 0 && r < c[q]) v = s_part[q][r];
        }
        s_idx[k] = v;
    }
    __syncthreads();

    if (total > 0 && total < SS) {
        for (int k = total + threadIdx.x; k < SS; k += 512)
            s_idx[k] = s_idx[k % total];
        __syncthreads();
    }

    // Epilogue: emit {idx, x, y, z} records (point table is L2-hot).
    float4* dst = rec_ws + (size_t)box * SS;
    const float* Pb = points + (size_t)b * NN * 3;
    for (int k = threadIdx.x; k < SS; k += 512) {
        const int id = s_idx[k];
        float4 r;
        r.x = __int_as_float(id);
        r.y = Pb[id * 3 + 0];
        r.z = Pb[id * 3 + 1];
        r.w = Pb[id * 3 + 2];
        dst[k] = r;
    }
    if (threadIdx.x == 0) {
        cnt_ws[box]   = total;
        flag_out[box] = (total == 0) ? 1.0f : 0.0f;
    }
}

// ---------------------------------------------------------------------------
// Kernel B: record-driven gather with swizzled-LDS staging -> dense aligned
// float4 stores. Grid: 8192 flat workgroups, XCD-affinity remapped (R10).
// 256 threads = 8 half-waves; half-wave hw owns samples k = 4*hw + s.
// Measured warm = 31.4us (R12), within ~10-20% of its write+L3-read floor.
// ---------------------------------------------------------------------------
__global__ __launch_bounds__(256)
void gather_kernel(const float4* __restrict__ rec_ws,  // (BM,SS) {idx,x,y,z}
                   const float* __restrict__ feats,    // (B,N,C)
                   const int*   __restrict__ cnt_ws,   // (BM)
                   float* __restrict__ out)            // (BM,SS,CH)
{
    const int flat  = blockIdx.x;
    const int r     = flat & 7;
    const int b     = r >> 1;
    const int s2    = ((flat >> 3) << 1) | (r & 1);
    const int m     = s2 & (MM - 1);
    const int chunk = s2 >> 7;            // 0..15
    const int box   = (b << 7) + m;

    const int tid   = threadIdx.x;
    const int hw    = tid >> 5;           // half-wave 0..7
    const int j     = tid & 31;           // lane in half-wave

    __shared__ float s_out[32 * CH];      // 4192 dwords = 16768 B

    const float scale = (cnt_ws[box] > 0) ? 1.0f : 0.0f;
    const float4* recp = rec_ws + (size_t)box * SS + chunk * 32;

    float4 rec[4];
    #pragma unroll
    for (int s = 0; s < 4; ++s) rec[s] = recp[4 * hw + s];   // broadcast loads

    const float4* F4 = (const float4*)(feats + (size_t)b * NN * CC);

    float4 v[4];
    #pragma unroll
    for (int s = 0; s < 4; ++s) v[s] = F4[__float_as_int(rec[s].x) * 32 + j];

    // Swizzled staging. Row k = 4*hw+s owns dwords [k*131, k*131+131).
    #pragma unroll
    for (int s = 0; s < 4; ++s) {
        const int k    = 4 * hw + s;
        const int base = k * CH + 3 + 4 * j;
        s_out[SWZ(base + 0)] = v[s].x * scale;
        s_out[SWZ(base + 1)] = v[s].y * scale;
        s_out[SWZ(base + 2)] = v[s].z * scale;
        s_out[SWZ(base + 3)] = v[s].w * scale;
        if (j < 3) {
            const float p = (j == 0) ? rec[s].y : ((j == 1) ? rec[s].z : rec[s].w);
            s_out[SWZ(k * CH + j)] = p * scale;
        }
    }
    __syncthreads();

    // Dense aligned output: 1048 float4s over the chunk's contiguous 16768 B.
    float* dst = out + (size_t)box * SS * CH + (size_t)chunk * 32 * CH;
    for (int t = tid; t < (32 * CH) / 4; t += 256) {
        const int dw = 4 * t;
        float4 o;
        o.x = s_out[SWZ(dw + 0)];
        o.y = s_out[SWZ(dw + 1)];
        o.z = s_out[SWZ(dw + 2)];
        o.w = s_out[SWZ(dw + 3)];
        ((float4*)dst)[t] = o;
    }
}

extern "C" void kernel_launch(void* const* d_in, const int* in_sizes, int n_in,
                              void* d_out, int out_size, void* d_ws, size_t ws_size,
                              hipStream_t stream) {
    const float* points = (const float*)d_in[0];
    const float* feats  = (const float*)d_in[1];
    const float* boxes  = (const float*)d_in[2];
    // d_in[3] = num_sampled_points, fixed at 512 by setup_inputs.

    float4* rec_ws = (float4*)d_ws;                  // BM*SS float4 = 4 MiB
    int*    cnt_ws = (int*)(rec_ws + (size_t)BM * SS); // BM ints
    float*  out      = (float*)d_out;
    float*  flag_out = out + (size_t)BM * SS * CH;   // empty_flag as float 0/1

    box_sample_kernel<<<BM, 512, 0, stream>>>(points, boxes, rec_ws, cnt_ws, flag_out);
    gather_kernel<<<BM * (SS / 32), 256, 0, stream>>>(rec_ws, feats, cnt_ws, out);
}